// Round 12
// baseline (108.265 us; speedup 1.0000x reference)
//
#include <hip/hip_runtime.h>

#define R_MAX 32
#define DIM_OUT 128
#define N_R 66              // 2*R_MAX + 2
#define DIM_IN 139          // 2*N_R + 1 + N_S
#define NBUCKET 65          // bucket in [0,64]

typedef float f32x4 __attribute__((ext_vector_type(4)));

// out[bi, i, j, d] = W[d, N_R + clip(i-j+32,0,64)] + (W[d,32] + W[d,132] + W[d,138])
// ~94% of (i,j) saturate the bucket -> two per-thread constant float4s (pure nt
// store stream, fillBuffer shape ~6.8 TB/s). The 65-wide diagonal band (~6%) is
// served from a per-block LDS table so its stores don't stall on scattered
// global W gathers (R11: band ran ~2 TB/s, costing ~14 us).
__global__ __launch_bounds__(256) void rpe_kernel(const int* __restrict__ p_seq,
                                                  const float* __restrict__ W,
                                                  f32x4* __restrict__ out,
                                                  unsigned long long n_rows) {
    __shared__ float cst_lds[DIM_OUT];
    __shared__ float table[NBUCKET * DIM_OUT];   // 33,280 B

    const unsigned seq = (unsigned)*p_seq;
    const unsigned tid = threadIdx.x;
    const unsigned lane = tid & 31;          // column group: floats [lane*4, lane*4+4)
    const float* w0 = W + (size_t)(lane * 4) * DIM_IN;

    // Per-thread constants for the saturated regions (exact reference association).
    float cst[4];
    f32x4 vhi, vlo;
    #pragma unroll
    for (int k = 0; k < 4; ++k) {
        const float* w = w0 + (size_t)k * DIM_IN;
        cst[k] = (w[R_MAX] + w[2 * N_R]) + w[DIM_IN - 1];
        vhi[k] = w[N_R + 2 * R_MAX] + cst[k];   // bucket 64 (j <= i-32)
        vlo[k] = w[N_R + 0] + cst[k];           // bucket 0  (j >= i+32)
    }

    // Band table build (off the hot path; W is L1/L2-resident).
    if (tid < DIM_OUT) {
        const float* w = W + (size_t)tid * DIM_IN;
        cst_lds[tid] = (w[R_MAX] + w[2 * N_R]) + w[DIM_IN - 1];
    }
    __syncthreads();
    for (int t = (int)tid; t < NBUCKET * DIM_OUT; t += 256) {
        const int b = t >> 7;
        const int d = t & (DIM_OUT - 1);
        table[t] = W[(size_t)d * DIM_IN + N_R + b] + cst_lds[d];
    }
    __syncthreads();

    const unsigned n_irows = (unsigned)(n_rows / seq);  // batch * seq
    const unsigned CPR = 2;                              // chunks per i-row
    const unsigned total_chunks = n_irows * CPR;

    for (unsigned chunk = blockIdx.x; chunk < total_chunks; chunk += gridDim.x) {
        const unsigned irow = chunk / CPR;
        const unsigned half = chunk - irow * CPR;
        const int i = (int)(irow % seq);
        const int j0 = (int)((half * seq) / CPR);
        const int j1 = (int)(((half + 1) * seq) / CPR);

        // j < i-31 -> vhi; j in [i-31, i+31] -> band; j >= i+32 -> vlo
        int e1 = i - 31; e1 = e1 < j0 ? j0 : (e1 > j1 ? j1 : e1);
        int e2 = i + 32; e2 = e2 < j0 ? j0 : (e2 > j1 ? j1 : e2);

        f32x4* __restrict__ base = out + (size_t)irow * seq * (DIM_OUT / 4);

        // region 1: pure store stream of vhi
        for (int f = j0 * 32 + (int)tid; f < e1 * 32; f += 256)
            __builtin_nontemporal_store(vhi, base + f);

        // region 2: band via LDS table (f&31 == lane, invariant under f+=256)
        for (int f = e1 * 32 + (int)tid; f < e2 * 32; f += 256) {
            const int j = f >> 5;
            const int b = i - j + R_MAX;            // in [1, 63]
            const f32x4 v = *reinterpret_cast<const f32x4*>(
                &table[(b << 7) + ((f & 31) << 2)]);
            __builtin_nontemporal_store(v, base + f);
        }

        // region 3: pure store stream of vlo
        for (int f = e2 * 32 + (int)tid; f < j1 * 32; f += 256)
            __builtin_nontemporal_store(vlo, base + f);
    }
}

extern "C" void kernel_launch(void* const* d_in, const int* in_sizes, int n_in,
                              void* d_out, int out_size, void* d_ws, size_t ws_size,
                              hipStream_t stream) {
    // Inputs per setup_inputs() order: batch_size (int), seq_len (int), W (float32)
    const int* p_seq = (const int*)d_in[1];
    const float* W = (const float*)d_in[2];
    f32x4* out = (f32x4*)d_out;

    const unsigned long long n_rows = (unsigned long long)out_size / DIM_OUT;

    // 2048 blocks: for seq=1024, exactly one 256 KB chunk per block.
    rpe_kernel<<<2048, 256, 0, stream>>>(p_seq, W, out, n_rows);
}